// Round 13
// baseline (118.060 us; speedup 1.0000x reference)
//
#include <hip/hip_runtime.h>
#include <math.h>

#define BATCH 16384
#define N0 57
#define NX 3249          // 57*57
#define HS 5
#define NCLS 17
#define NTRI 15
#define EPSV 1e-4f

// ---------------------------------------------------------------- helpers
template<int CTRL>
__device__ __forceinline__ float dpp_mov0(float x) {
    return __int_as_float(__builtin_amdgcn_update_dpp(
        0, __float_as_int(x), CTRL, 0xF, 0xF, true));
}
// full 64-lane sum, result valid in lane 63, pure VALU (no LDS pipe)
__device__ __forceinline__ float wave_sum64(float x) {
    x += dpp_mov0<0x111>(x);   // row_shr:1
    x += dpp_mov0<0x112>(x);   // row_shr:2
    x += dpp_mov0<0x114>(x);   // row_shr:4
    x += dpp_mov0<0x118>(x);   // row_shr:8
    x += dpp_mov0<0x142>(x);   // row_bcast:15
    x += dpp_mov0<0x143>(x);   // row_bcast:31 -> lane 63 = total
    return x;
}

__device__ __forceinline__ float frcp(float x)  { return __builtin_amdgcn_rcpf(x); }
__device__ __forceinline__ float frsq(float x)  { return __builtin_amdgcn_rsqf(x); }
__device__ __forceinline__ float fsqrt(float x) { return __builtin_amdgcn_sqrtf(x); }

// ------------------------------------------------------------------ k_all
// Phase 1 (R11-identical): per-block wc preamble; wave w streams matrix
// blk*4+w with full-row coalesced dword reads, column scheme, DPP reduce.
// Phase 2: lane-63s drop p[] into LDS; threads 0-3 (wave 0) run the four
// 5x5 Jacobi eigs SIMT — per-BLOCK granularity (4096 instances), issue
// hidden under co-resident blocks' streaming. (R7/R8 failed because eig
// was per-WAVE: 16384 instances x 64-lane divergence.)
__global__ __launch_bounds__(256) void k_all(const float* __restrict__ x,
                                             const float* __restrict__ W1,
                                             const float* __restrict__ W2,
                                             const float* __restrict__ W3,
                                             const float* __restrict__ lin_w,
                                             const float* __restrict__ lin_b,
                                             float* __restrict__ out) {
    __shared__ float w23[100];        // W2@W3 (20x5)
    __shared__ float wcs[N0 * 8];     // wc rows padded to 8
    __shared__ float yb[4][16];       // per-wave bilinear results
    const int tid  = threadIdx.x;
    const int lane = tid & 63;
    const int wave = tid >> 6;
    const int m    = blockIdx.x * 4 + wave;

    // ---- preamble: wc into LDS (R11-proven)
    if (tid < 100) {
        int k = tid / 5, j = tid % 5;
        float acc = 0.f;
        #pragma unroll
        for (int l = 0; l < 10; ++l) acc = fmaf(W2[k * 10 + l], W3[l * 5 + j], acc);
        w23[tid] = acc;
    }
    __syncthreads();
    if (tid < N0) {
        #pragma unroll
        for (int j = 0; j < 5; ++j) {
            float acc = 0.f;
            #pragma unroll
            for (int k = 0; k < 20; ++k) acc = fmaf(W1[tid * 20 + k], w23[k * 5 + j], acc);
            wcs[tid * 8 + j] = acc;
        }
    }
    __syncthreads();

    // per-lane Wc row
    float wv[HS];
    {
        int a = (lane < N0) ? lane : 0;
        #pragma unroll
        for (int i = 0; i < HS; ++i) wv[i] = wcs[a * 8 + i];
        if (lane >= N0) { wv[0] = wv[1] = wv[2] = wv[3] = wv[4] = 0.f; }
    }

    // ---- stream one matrix per wave: 57 coalesced 64-dword reads
    const int lc = (lane < N0) ? lane : 56;
    const float* base = x + (size_t)m * NX + lc;
    float s[HS] = {0.f, 0.f, 0.f, 0.f, 0.f};
    #pragma unroll
    for (int b = 0; b < N0; ++b) {
        float xv = base[b * N0];
        #pragma unroll
        for (int j = 0; j < HS; ++j) s[j] = fmaf(xv, wcs[b * 8 + j], s[j]);
    }

    // upper-tri outer product + DPP reduction
    float p[NTRI];
    int u = 0;
    #pragma unroll
    for (int i = 0; i < HS; ++i)
        #pragma unroll
        for (int j = i; j < HS; ++j) { p[u] = wave_sum64(wv[i] * s[j]); ++u; }

    if (lane == 63) {
        #pragma unroll
        for (int k = 0; k < NTRI; ++k) yb[wave][k] = p[k];
    }
    __syncthreads();

    // ---- phase 2: threads 0-3 run the block's four eigs SIMT
    if (tid < 4) {
        const int me = blockIdx.x * 4 + tid;
        float A[HS][HS], V[HS][HS];
        int t = 0;
        #pragma unroll
        for (int i = 0; i < HS; ++i)
            #pragma unroll
            for (int j = i; j < HS; ++j) {
                float v = yb[tid][t];
                A[i][j] = v; A[j][i] = v; ++t;
            }
        #pragma unroll
        for (int i = 0; i < HS; ++i)
            #pragma unroll
            for (int j = 0; j < HS; ++j) V[i][j] = (i == j) ? 1.f : 0.f;

        #pragma unroll
        for (int sweep = 0; sweep < 5; ++sweep) {
            #pragma unroll
            for (int pp = 0; pp < HS - 1; ++pp) {
                #pragma unroll
                for (int q = pp + 1; q < HS; ++q) {
                    float apq = A[pp][q];
                    float app = A[pp][pp], aqq = A[q][q];
                    bool nz = fabsf(apq) > 1e-30f;
                    float theta = (aqq - app) * 0.5f * frcp(apq);
                    float tt = frcp(fabsf(theta) + fsqrt(fmaf(theta, theta, 1.f)));
                    tt = copysignf(tt, theta);
                    tt = nz ? tt : 0.f;
                    float c = frsq(fmaf(tt, tt, 1.f));
                    float sn = tt * c;
                    #pragma unroll
                    for (int k = 0; k < HS; ++k) {
                        float akp = A[k][pp], akq = A[k][q];
                        A[k][pp] = fmaf(c, akp, -sn * akq);
                        A[k][q]  = fmaf(sn, akp,  c * akq);
                    }
                    #pragma unroll
                    for (int k = 0; k < HS; ++k) {
                        float apk = A[pp][k], aqk = A[q][k];
                        A[pp][k] = fmaf(c, apk, -sn * aqk);
                        A[q][k]  = fmaf(sn, apk,  c * aqk);
                    }
                    #pragma unroll
                    for (int k = 0; k < HS; ++k) {
                        float vkp = V[k][pp], vkq = V[k][q];
                        V[k][pp] = fmaf(c, vkp, -sn * vkq);
                        V[k][q]  = fmaf(sn, vkp,  c * vkq);
                    }
                }
            }
        }

        float lwv[HS];
        #pragma unroll
        for (int i = 0; i < HS; ++i)
            lwv[i] = 0.69314718056f * __log2f(fmaxf(A[i][i], EPSV));

        float tri2[NTRI];
        t = 0;
        #pragma unroll
        for (int i = 0; i < HS; ++i) {
            float vi[HS];
            #pragma unroll
            for (int k = 0; k < HS; ++k) vi[k] = V[i][k] * lwv[k];
            #pragma unroll
            for (int j = i; j < HS; ++j) {
                float acc = 0.f;
                #pragma unroll
                for (int k = 0; k < HS; ++k) acc = fmaf(vi[k], V[j][k], acc);
                tri2[t++] = acc;
            }
        }

        #pragma unroll
        for (int c = 0; c < NCLS; ++c) {
            float acc = lin_b[c];
            #pragma unroll
            for (int k = 0; k < NTRI; ++k) acc = fmaf(tri2[k], lin_w[c * NTRI + k], acc);
            out[(size_t)me * NCLS + c] = acc;
        }
    }
}

// ----------------------------------------------------------------- launch
extern "C" void kernel_launch(void* const* d_in, const int* in_sizes, int n_in,
                              void* d_out, int out_size, void* d_ws, size_t ws_size,
                              hipStream_t stream) {
    const float* x     = (const float*)d_in[0];
    const float* W1    = (const float*)d_in[1];
    const float* W2    = (const float*)d_in[2];
    const float* W3    = (const float*)d_in[3];
    const float* lin_w = (const float*)d_in[4];
    const float* lin_b = (const float*)d_in[5];
    float* out = (float*)d_out;

    k_all<<<BATCH / 4, 256, 0, stream>>>(x, W1, W2, W3, lin_w, lin_b, out);
}

// Round 14
// 52.447 us; speedup vs baseline: 2.2510x; 2.2510x over previous
//
#include <hip/hip_runtime.h>
#include <math.h>

#define BATCH 16384
#define N0 57
#define NX 3249          // 57*57
#define HS 5
#define NCLS 17
#define NTRI 15
#define EPSV 1e-4f

// ---------------------------------------------------------------- helpers
template<int CTRL>
__device__ __forceinline__ float dpp_mov0(float x) {
    return __int_as_float(__builtin_amdgcn_update_dpp(
        0, __float_as_int(x), CTRL, 0xF, 0xF, true));
}
// full 64-lane sum, result valid in lane 63, pure VALU (no LDS pipe)
__device__ __forceinline__ float wave_sum64(float x) {
    x += dpp_mov0<0x111>(x);   // row_shr:1
    x += dpp_mov0<0x112>(x);   // row_shr:2
    x += dpp_mov0<0x114>(x);   // row_shr:4
    x += dpp_mov0<0x118>(x);   // row_shr:8
    x += dpp_mov0<0x142>(x);   // row_bcast:15
    x += dpp_mov0<0x143>(x);   // row_bcast:31 -> lane 63 = total
    return x;
}

__device__ __forceinline__ float frcp(float x)  { return __builtin_amdgcn_rcpf(x); }
__device__ __forceinline__ float frsq(float x)  { return __builtin_amdgcn_rsqf(x); }
__device__ __forceinline__ float fsqrt(float x) { return __builtin_amdgcn_sqrtf(x); }

// ----------------------------------------------------------------- k_main
// VECTORIZED x read: matrix = 3249 contiguous floats; rows 0..55 = 14
// blocks of 228 floats (57 aligned float4 each). Lane i owns the float4 at
// 228*it + 4i: its 4 element-columns col[c]=(4i+c)%57 are FIXED per lane;
// row = 4it + r0[c] varies -> wc[row][j] from LDS b128 (<=4 distinct rows,
// distinct banks). s4[c][j] accumulates column-partial sums; epilogue
// contracts with wv4[c][i]=wc[col][i] and adds the row-56 tail, then DPP
// wave-reduce. VMEM instrs per matrix: 57 dword -> 15 (14 dwordx4 + 1).
__global__ __launch_bounds__(256) void k_main(const float* __restrict__ x,
                                              const float* __restrict__ W1,
                                              const float* __restrict__ W2,
                                              const float* __restrict__ W3,
                                              float* __restrict__ y_out) {
    __shared__ float  w23[100];       // W2@W3 (20x5)
    __shared__ float4 wcs4[N0];       // wc[row][0..3]
    __shared__ float  wcs1[N0];       // wc[row][4]
    const int tid  = threadIdx.x;
    const int lane = tid & 63;
    const int wave = tid >> 6;
    const int m    = blockIdx.x * 4 + wave;

    // ---- preamble: wc into LDS
    if (tid < 100) {
        int k = tid / 5, j = tid % 5;
        float acc = 0.f;
        #pragma unroll
        for (int l = 0; l < 10; ++l) acc = fmaf(W2[k * 10 + l], W3[l * 5 + j], acc);
        w23[tid] = acc;
    }
    __syncthreads();
    if (tid < N0) {
        float r[5];
        #pragma unroll
        for (int j = 0; j < 5; ++j) {
            float acc = 0.f;
            #pragma unroll
            for (int k = 0; k < 20; ++k) acc = fmaf(W1[tid * 20 + k], w23[k * 5 + j], acc);
            r[j] = acc;
        }
        wcs4[tid] = make_float4(r[0], r[1], r[2], r[3]);
        wcs1[tid] = r[4];
    }
    __syncthreads();

    // ---- per-lane constants
    const bool act = lane < N0;
    const int  e0  = 4 * lane;                    // element base in each 228-block
    int col[4], r0[4];
    #pragma unroll
    for (int c = 0; c < 4; ++c) {
        int ec = e0 + c;
        r0[c]  = ec / N0;                         // 0..4 (>=57 lanes: 4)
        col[c] = ec - r0[c] * N0;                 // fixed column per (lane,c)
    }
    float wv4[4][HS];
    #pragma unroll
    for (int c = 0; c < 4; ++c) {
        float4 t4 = wcs4[col[c]]; float t1 = wcs1[col[c]];
        wv4[c][0] = act ? t4.x : 0.f;  wv4[c][1] = act ? t4.y : 0.f;
        wv4[c][2] = act ? t4.z : 0.f;  wv4[c][3] = act ? t4.w : 0.f;
        wv4[c][4] = act ? t1   : 0.f;
    }
    float wva[HS];
    {
        int a = act ? lane : 0;
        float4 t4 = wcs4[a]; float t1 = wcs1[a];
        wva[0] = act ? t4.x : 0.f;  wva[1] = act ? t4.y : 0.f;
        wva[2] = act ? t4.z : 0.f;  wva[3] = act ? t4.w : 0.f;
        wva[4] = act ? t1   : 0.f;
    }

    // ---- main loop: rows 0..55 as 14 x 228-float blocks, dwordx4 loads
    const float* mb = x + (size_t)m * NX;
    float s4[4][HS];
    #pragma unroll
    for (int c = 0; c < 4; ++c)
        #pragma unroll
        for (int j = 0; j < HS; ++j) s4[c][j] = 0.f;

    #pragma unroll
    for (int it = 0; it < 14; ++it) {
        float4 xq = *(const float4*)(mb + 228 * it + e0);   // 16B-aligned
        float xe[4] = {xq.x, xq.y, xq.z, xq.w};
        #pragma unroll
        for (int c = 0; c < 4; ++c) {
            int rc = 4 * it + r0[c];                        // <=55 act, <=56 inact
            float4 w4 = wcs4[rc]; float w1 = wcs1[rc];
            s4[c][0] = fmaf(xe[c], w4.x, s4[c][0]);
            s4[c][1] = fmaf(xe[c], w4.y, s4[c][1]);
            s4[c][2] = fmaf(xe[c], w4.z, s4[c][2]);
            s4[c][3] = fmaf(xe[c], w4.w, s4[c][3]);
            s4[c][4] = fmaf(xe[c], w1,   s4[c][4]);
        }
    }

    // ---- tail: row 56 (coalesced dwords, column scheme)
    float st[HS];
    {
        float xv = mb[3192 + (act ? lane : 56)];
        float4 w4 = wcs4[56]; float w1 = wcs1[56];
        st[0] = xv * w4.x; st[1] = xv * w4.y; st[2] = xv * w4.z;
        st[3] = xv * w4.w; st[4] = xv * w1;
    }

    // ---- epilogue: contract + DPP reduce
    float p[NTRI];
    int u = 0;
    #pragma unroll
    for (int i = 0; i < HS; ++i)
        #pragma unroll
        for (int j = i; j < HS; ++j) {
            float v = wva[i] * st[j];
            #pragma unroll
            for (int c = 0; c < 4; ++c) v = fmaf(wv4[c][i], s4[c][j], v);
            p[u] = wave_sum64(v);
            ++u;
        }

    if (lane == 63) {
        float4* o = (float4*)&y_out[(size_t)m * 16];
        o[0] = make_float4(p[0],  p[1],  p[2],  p[3]);
        o[1] = make_float4(p[4],  p[5],  p[6],  p[7]);
        o[2] = make_float4(p[8],  p[9],  p[10], p[11]);
        o[3] = make_float4(p[12], p[13], p[14], 0.f);
    }
}

// ------------------------------------------------------------------ k_eig
// R11-proven: one thread per matrix, SIMT-packed, 5 sweeps, fast-math.
__global__ __launch_bounds__(64) void k_eig(const float* __restrict__ y_in,
                                            const float* __restrict__ lin_w,
                                            const float* __restrict__ lin_b,
                                            float* __restrict__ out) {
    int m = blockIdx.x * 64 + threadIdx.x;
    const float4* yin = (const float4*)&y_in[(size_t)m * 16];
    float4 q0 = yin[0], q1 = yin[1], q2 = yin[2], q3 = yin[3];
    float tri[16] = {q0.x, q0.y, q0.z, q0.w, q1.x, q1.y, q1.z, q1.w,
                     q2.x, q2.y, q2.z, q2.w, q3.x, q3.y, q3.z, q3.w};

    float A[HS][HS], V[HS][HS];
    int t = 0;
    #pragma unroll
    for (int i = 0; i < HS; ++i)
        #pragma unroll
        for (int j = i; j < HS; ++j) { A[i][j] = tri[t]; A[j][i] = tri[t]; ++t; }
    #pragma unroll
    for (int i = 0; i < HS; ++i)
        #pragma unroll
        for (int j = 0; j < HS; ++j) V[i][j] = (i == j) ? 1.f : 0.f;

    #pragma unroll
    for (int sweep = 0; sweep < 5; ++sweep) {
        #pragma unroll
        for (int p = 0; p < HS - 1; ++p) {
            #pragma unroll
            for (int q = p + 1; q < HS; ++q) {
                float apq = A[p][q];
                float app = A[p][p], aqq = A[q][q];
                bool nz = fabsf(apq) > 1e-30f;
                float theta = (aqq - app) * 0.5f * frcp(apq);
                float tt = frcp(fabsf(theta) + fsqrt(fmaf(theta, theta, 1.f)));
                tt = copysignf(tt, theta);
                tt = nz ? tt : 0.f;
                float c = frsq(fmaf(tt, tt, 1.f));
                float sn = tt * c;
                #pragma unroll
                for (int k = 0; k < HS; ++k) {
                    float akp = A[k][p], akq = A[k][q];
                    A[k][p] = fmaf(c, akp, -sn * akq);
                    A[k][q] = fmaf(sn, akp,  c * akq);
                }
                #pragma unroll
                for (int k = 0; k < HS; ++k) {
                    float apk = A[p][k], aqk = A[q][k];
                    A[p][k] = fmaf(c, apk, -sn * aqk);
                    A[q][k] = fmaf(sn, apk,  c * aqk);
                }
                #pragma unroll
                for (int k = 0; k < HS; ++k) {
                    float vkp = V[k][p], vkq = V[k][q];
                    V[k][p] = fmaf(c, vkp, -sn * vkq);
                    V[k][q] = fmaf(sn, vkp,  c * vkq);
                }
            }
        }
    }

    float lwv[HS];
    #pragma unroll
    for (int i = 0; i < HS; ++i)
        lwv[i] = 0.69314718056f * __log2f(fmaxf(A[i][i], EPSV));

    float tri2[NTRI];
    t = 0;
    #pragma unroll
    for (int i = 0; i < HS; ++i) {
        float vi[HS];
        #pragma unroll
        for (int k = 0; k < HS; ++k) vi[k] = V[i][k] * lwv[k];
        #pragma unroll
        for (int j = i; j < HS; ++j) {
            float acc = 0.f;
            #pragma unroll
            for (int k = 0; k < HS; ++k) acc = fmaf(vi[k], V[j][k], acc);
            tri2[t++] = acc;
        }
    }

    #pragma unroll
    for (int c = 0; c < NCLS; ++c) {
        float acc = lin_b[c];
        #pragma unroll
        for (int k = 0; k < NTRI; ++k) acc = fmaf(tri2[k], lin_w[c * NTRI + k], acc);
        out[(size_t)m * NCLS + c] = acc;
    }
}

// ----------------------------------------------------------------- launch
extern "C" void kernel_launch(void* const* d_in, const int* in_sizes, int n_in,
                              void* d_out, int out_size, void* d_ws, size_t ws_size,
                              hipStream_t stream) {
    const float* x     = (const float*)d_in[0];
    const float* W1    = (const float*)d_in[1];
    const float* W2    = (const float*)d_in[2];
    const float* W3    = (const float*)d_in[3];
    const float* lin_w = (const float*)d_in[4];
    const float* lin_b = (const float*)d_in[5];
    float* out = (float*)d_out;
    float* y   = (float*)d_ws;     // 16384*16 floats

    k_main<<<BATCH / 4, 256, 0, stream>>>(x, W1, W2, W3, y);
    k_eig<<<BATCH / 64, 64, 0, stream>>>(y, lin_w, lin_b, out);
}

// Round 15
// 47.105 us; speedup vs baseline: 2.5063x; 1.1134x over previous
//
#include <hip/hip_runtime.h>
#include <math.h>

#define BATCH 16384
#define N0 57
#define NX 3249          // 57*57
#define HS 5
#define NCLS 17
#define NTRI 15
#define EPSV 1e-4f

// ---------------------------------------------------------------- helpers
template<int CTRL>
__device__ __forceinline__ float dpp_mov0(float x) {
    return __int_as_float(__builtin_amdgcn_update_dpp(
        0, __float_as_int(x), CTRL, 0xF, 0xF, true));
}
// full 64-lane sum, result valid in lane 63, pure VALU (no LDS pipe)
__device__ __forceinline__ float wave_sum64(float x) {
    x += dpp_mov0<0x111>(x);   // row_shr:1
    x += dpp_mov0<0x112>(x);   // row_shr:2
    x += dpp_mov0<0x114>(x);   // row_shr:4
    x += dpp_mov0<0x118>(x);   // row_shr:8
    x += dpp_mov0<0x142>(x);   // row_bcast:15
    x += dpp_mov0<0x143>(x);   // row_bcast:31 -> lane 63 = total
    return x;
}

__device__ __forceinline__ float frcp(float x)  { return __builtin_amdgcn_rcpf(x); }
__device__ __forceinline__ float frsq(float x)  { return __builtin_amdgcn_rsqf(x); }
__device__ __forceinline__ float fsqrt(float x) { return __builtin_amdgcn_sqrtf(x); }

// ----------------------------------------------------------------- k_main
// R11-identical structure (best: 48.1 µs total) + XCD-aware blockIdx
// swizzle: grid 4096 % 8 == 0 -> bijective; each XCD streams one contiguous
// 26.6 MB chunk of x (DRAM page/channel locality probe, T1).
__global__ __launch_bounds__(256) void k_main(const float* __restrict__ x,
                                              const float* __restrict__ W1,
                                              const float* __restrict__ W2,
                                              const float* __restrict__ W3,
                                              float* __restrict__ y_out) {
    __shared__ float w23[100];        // W2@W3 (20x5)
    __shared__ float wcs[N0 * 8];     // wc rows padded to 8
    const int tid  = threadIdx.x;
    const int lane = tid & 63;
    const int wave = tid >> 6;
    // XCD swizzle: bid%8 = XCD slot -> contiguous chunk of 512 blocks
    const int bid  = blockIdx.x;
    const int swz  = (bid & 7) * (4096 >> 3) + (bid >> 3);
    const int m    = swz * 4 + wave;

    // ---- preamble: wc into LDS (R11-proven)
    if (tid < 100) {
        int k = tid / 5, j = tid % 5;
        float acc = 0.f;
        #pragma unroll
        for (int l = 0; l < 10; ++l) acc = fmaf(W2[k * 10 + l], W3[l * 5 + j], acc);
        w23[tid] = acc;
    }
    __syncthreads();
    if (tid < N0) {
        #pragma unroll
        for (int j = 0; j < 5; ++j) {
            float acc = 0.f;
            #pragma unroll
            for (int k = 0; k < 20; ++k) acc = fmaf(W1[tid * 20 + k], w23[k * 5 + j], acc);
            wcs[tid * 8 + j] = acc;
        }
    }
    __syncthreads();

    // per-lane Wc row (left operand of the outer product)
    float wv[HS];
    {
        int a = (lane < N0) ? lane : 0;
        #pragma unroll
        for (int i = 0; i < HS; ++i) wv[i] = wcs[a * 8 + i];
        if (lane >= N0) { wv[0] = wv[1] = wv[2] = wv[3] = wv[4] = 0.f; }
    }

    // ---- stream one matrix per wave: 57 coalesced 64-dword reads
    const int lc = (lane < N0) ? lane : 56;          // clamp keeps loads in-bounds
    const float* base = x + (size_t)m * NX + lc;
    float s[HS] = {0.f, 0.f, 0.f, 0.f, 0.f};
    #pragma unroll
    for (int b = 0; b < N0; ++b) {
        float xv = base[b * N0];
        #pragma unroll
        for (int j = 0; j < HS; ++j) s[j] = fmaf(xv, wcs[b * 8 + j], s[j]);
    }

    // upper-tri outer product + DPP reduction (VALU only)
    float p[NTRI];
    int u = 0;
    #pragma unroll
    for (int i = 0; i < HS; ++i)
        #pragma unroll
        for (int j = i; j < HS; ++j) { p[u] = wave_sum64(wv[i] * s[j]); ++u; }

    if (lane == 63) {
        float4* o = (float4*)&y_out[(size_t)m * 16];
        o[0] = make_float4(p[0],  p[1],  p[2],  p[3]);
        o[1] = make_float4(p[4],  p[5],  p[6],  p[7]);
        o[2] = make_float4(p[8],  p[9],  p[10], p[11]);
        o[3] = make_float4(p[12], p[13], p[14], 0.f);
    }
}

// ------------------------------------------------------------------ k_eig
// One thread per matrix, SIMT-packed. 4 cyclic sweeps (quadratic regime by
// sweep 3; R14 absmax margin 10x). Fast-math natives; lin_w/lin_b s_load.
__global__ __launch_bounds__(64) void k_eig(const float* __restrict__ y_in,
                                            const float* __restrict__ lin_w,
                                            const float* __restrict__ lin_b,
                                            float* __restrict__ out) {
    int m = blockIdx.x * 64 + threadIdx.x;
    const float4* yin = (const float4*)&y_in[(size_t)m * 16];
    float4 q0 = yin[0], q1 = yin[1], q2 = yin[2], q3 = yin[3];
    float tri[16] = {q0.x, q0.y, q0.z, q0.w, q1.x, q1.y, q1.z, q1.w,
                     q2.x, q2.y, q2.z, q2.w, q3.x, q3.y, q3.z, q3.w};

    float A[HS][HS], V[HS][HS];
    int t = 0;
    #pragma unroll
    for (int i = 0; i < HS; ++i)
        #pragma unroll
        for (int j = i; j < HS; ++j) { A[i][j] = tri[t]; A[j][i] = tri[t]; ++t; }
    #pragma unroll
    for (int i = 0; i < HS; ++i)
        #pragma unroll
        for (int j = 0; j < HS; ++j) V[i][j] = (i == j) ? 1.f : 0.f;

    #pragma unroll
    for (int sweep = 0; sweep < 4; ++sweep) {
        #pragma unroll
        for (int p = 0; p < HS - 1; ++p) {
            #pragma unroll
            for (int q = p + 1; q < HS; ++q) {
                float apq = A[p][q];
                float app = A[p][p], aqq = A[q][q];
                bool nz = fabsf(apq) > 1e-30f;
                float theta = (aqq - app) * 0.5f * frcp(apq);
                float tt = frcp(fabsf(theta) + fsqrt(fmaf(theta, theta, 1.f)));
                tt = copysignf(tt, theta);
                tt = nz ? tt : 0.f;
                float c = frsq(fmaf(tt, tt, 1.f));
                float sn = tt * c;
                #pragma unroll
                for (int k = 0; k < HS; ++k) {
                    float akp = A[k][p], akq = A[k][q];
                    A[k][p] = fmaf(c, akp, -sn * akq);
                    A[k][q] = fmaf(sn, akp,  c * akq);
                }
                #pragma unroll
                for (int k = 0; k < HS; ++k) {
                    float apk = A[p][k], aqk = A[q][k];
                    A[p][k] = fmaf(c, apk, -sn * aqk);
                    A[q][k] = fmaf(sn, apk,  c * aqk);
                }
                #pragma unroll
                for (int k = 0; k < HS; ++k) {
                    float vkp = V[k][p], vkq = V[k][q];
                    V[k][p] = fmaf(c, vkp, -sn * vkq);
                    V[k][q] = fmaf(sn, vkp,  c * vkq);
                }
            }
        }
    }

    float lwv[HS];
    #pragma unroll
    for (int i = 0; i < HS; ++i)
        lwv[i] = 0.69314718056f * __log2f(fmaxf(A[i][i], EPSV));

    float tri2[NTRI];
    t = 0;
    #pragma unroll
    for (int i = 0; i < HS; ++i) {
        float vi[HS];
        #pragma unroll
        for (int k = 0; k < HS; ++k) vi[k] = V[i][k] * lwv[k];
        #pragma unroll
        for (int j = i; j < HS; ++j) {
            float acc = 0.f;
            #pragma unroll
            for (int k = 0; k < HS; ++k) acc = fmaf(vi[k], V[j][k], acc);
            tri2[t++] = acc;
        }
    }

    #pragma unroll
    for (int c = 0; c < NCLS; ++c) {
        float acc = lin_b[c];
        #pragma unroll
        for (int k = 0; k < NTRI; ++k) acc = fmaf(tri2[k], lin_w[c * NTRI + k], acc);
        out[(size_t)m * NCLS + c] = acc;
    }
}

// ----------------------------------------------------------------- launch
extern "C" void kernel_launch(void* const* d_in, const int* in_sizes, int n_in,
                              void* d_out, int out_size, void* d_ws, size_t ws_size,
                              hipStream_t stream) {
    const float* x     = (const float*)d_in[0];
    const float* W1    = (const float*)d_in[1];
    const float* W2    = (const float*)d_in[2];
    const float* W3    = (const float*)d_in[3];
    const float* lin_w = (const float*)d_in[4];
    const float* lin_b = (const float*)d_in[5];
    float* out = (float*)d_out;
    float* y   = (float*)d_ws;     // 16384*16 floats

    k_main<<<BATCH / 4, 256, 0, stream>>>(x, W1, W2, W3, y);
    k_eig<<<BATCH / 64, 64, 0, stream>>>(y, lin_w, lin_b, out);
}